// Round 1
// baseline (283.515 us; speedup 1.0000x reference)
//
#include <hip/hip_runtime.h>

#define NTHREADS 256
#define CHUNKS 8
#define TILE 1024

// Build packed float4 {x, y, z, |p|^2} arrays for both point sets.
__global__ __launch_bounds__(NTHREADS) void prep_kernel(
        const float* __restrict__ a, const float* __restrict__ b,
        float4* __restrict__ pa, float4* __restrict__ pb, int n) {
    int idx = blockIdx.x * blockDim.x + threadIdx.x;
    if (idx < n) {
        float x = a[3 * idx], y = a[3 * idx + 1], z = a[3 * idx + 2];
        pa[idx] = make_float4(x, y, z, x * x + y * y + z * z);
    } else if (idx < 2 * n) {
        int i = idx - n;
        float x = b[3 * i], y = b[3 * i + 1], z = b[3 * i + 2];
        pb[i] = make_float4(x, y, z, x * x + y * y + z * z);
    }
}

// Each block: 256 source points x one target chunk (n/CHUNKS targets),
// staged through LDS in TILE-point tiles. Inner loop: 3 FMA + 1 min.
// min_t(|s|^2+|t|^2-2 s.t) = |s|^2 + min_t(|t|^2 - 2 s.t)
__global__ __launch_bounds__(NTHREADS) void minpass_kernel(
        const float4* __restrict__ pa, const float4* __restrict__ pb,
        float* __restrict__ pmins, int n) {
    const int NB = n / NTHREADS;
    int b = blockIdx.x;
    int dir = b / (CHUNKS * NB);
    int rem = b % (CHUNKS * NB);
    int chunk = rem / NB;
    int sblk = rem % NB;
    const float4* __restrict__ src = dir ? pb : pa;
    const float4* __restrict__ tgt = dir ? pa : pb;
    int si = sblk * NTHREADS + threadIdx.x;
    float4 s = src[si];
    float ax = -2.0f * s.x, ay = -2.0f * s.y, az = -2.0f * s.z;
    const int CH = n / CHUNKS;
    __shared__ float4 tile[TILE];
    float m = __builtin_inff();
    int base = chunk * CH;
    for (int t = 0; t < CH; t += TILE) {
        for (int i = threadIdx.x; i < TILE; i += NTHREADS)
            tile[i] = tgt[base + t + i];
        __syncthreads();
#pragma unroll 8
        for (int j = 0; j < TILE; ++j) {
            float4 p = tile[j];  // broadcast ds_read_b128, conflict-free
            float d = fmaf(ax, p.x, fmaf(ay, p.y, fmaf(az, p.z, p.w)));
            m = fminf(m, d);
        }
        __syncthreads();
    }
    pmins[(dir * CHUNKS + chunk) * n + si] = m + s.w;
}

// Min over chunks, block-sum, atomicAdd per direction; last block finalizes.
__global__ __launch_bounds__(NTHREADS) void reduce_kernel(
        const float* __restrict__ pmins, float* acc, unsigned* cnt,
        float* out, int n, int nblocks) {
    const int NB = n / NTHREADS;
    int dir = blockIdx.x / NB;
    int sblk = blockIdx.x % NB;
    int i = sblk * NTHREADS + threadIdx.x;
    float m = __builtin_inff();
#pragma unroll
    for (int c = 0; c < CHUNKS; ++c)
        m = fminf(m, pmins[(dir * CHUNKS + c) * n + i]);
    // wave-64 shuffle reduction
    for (int off = 32; off > 0; off >>= 1)
        m += __shfl_down(m, off, 64);
    __shared__ float wsum[NTHREADS / 64];
    int lane = threadIdx.x & 63, wid = threadIdx.x >> 6;
    if (lane == 0) wsum[wid] = m;
    __syncthreads();
    if (threadIdx.x == 0) {
        float sum = 0.0f;
        for (int w = 0; w < NTHREADS / 64; ++w) sum += wsum[w];
        atomicAdd(&acc[dir], sum);
        __threadfence();
        unsigned old = atomicAdd(cnt, 1u);
        if (old == (unsigned)(nblocks - 1)) {
            __threadfence();
            float a0 = atomicAdd(&acc[0], 0.0f);  // device-scope coherent read
            float a1 = atomicAdd(&acc[1], 0.0f);
            out[0] = 0.5f * (a0 / n + a1 / n);
        }
    }
}

extern "C" void kernel_launch(void* const* d_in, const int* in_sizes, int n_in,
                              void* d_out, int out_size, void* d_ws, size_t ws_size,
                              hipStream_t stream) {
    const float* a = (const float*)d_in[0];
    const float* b = (const float*)d_in[1];
    int n = in_sizes[0] / 3;  // 16384 (== in_sizes[1]/3)
    float* out = (float*)d_out;
    char* ws = (char*)d_ws;
    float* acc = (float*)ws;                 // 2 floats
    unsigned* cnt = (unsigned*)(ws + 8);     // 1 uint
    float4* pa = (float4*)(ws + 256);
    float4* pb = pa + n;
    float* pmins = (float*)(ws + 256 + 2 * (size_t)n * sizeof(float4));

    hipMemsetAsync(ws, 0, 16, stream);
    prep_kernel<<<(2 * n + NTHREADS - 1) / NTHREADS, NTHREADS, 0, stream>>>(a, b, pa, pb, n);
    int NB = n / NTHREADS;
    minpass_kernel<<<2 * CHUNKS * NB, NTHREADS, 0, stream>>>(pa, pb, pmins, n);
    reduce_kernel<<<2 * NB, NTHREADS, 0, stream>>>(pmins, acc, cnt, out, n, 2 * NB);
}

// Round 2
// 102.440 us; speedup vs baseline: 2.7676x; 2.7676x over previous
//
#include <hip/hip_runtime.h>

#define TPB 256
#define R 8          // source points per lane
#define CHUNKS 64    // target-dim chunking for grid parallelism
// n=16384: SB = n/(TPB*R) = 8 source-blocks/dir; CH = n/CHUNKS = 256 targets/chunk
// grid = 2*SB*CHUNKS = 1024 blocks = 4 blocks/CU, 16 waves/CU

// Pack {x,y,z,|p|^2} for both sets; init pmins to +inf (idx covers exactly 2n).
__global__ __launch_bounds__(TPB) void prep_kernel(
        const float* __restrict__ a, const float* __restrict__ b,
        float4* __restrict__ pa, float4* __restrict__ pb,
        int* __restrict__ pmins, int n) {
    int idx = blockIdx.x * blockDim.x + threadIdx.x;
    if (idx < n) {
        float x = a[3 * idx], y = a[3 * idx + 1], z = a[3 * idx + 2];
        pa[idx] = make_float4(x, y, z, x * x + y * y + z * z);
    } else if (idx < 2 * n) {
        int i = idx - n;
        float x = b[3 * i], y = b[3 * i + 1], z = b[3 * i + 2];
        pb[i] = make_float4(x, y, z, x * x + y * y + z * z);
    }
    if (idx < 2 * n) pmins[idx] = 0x7f800000;  // +inf
}

// min_t(|s-t|^2) = |s|^2 + min_t(|t|^2 - 2 s.t)
// Each lane owns R=8 sources; one broadcast ds_read_b128 feeds 8x(3 FMA + min).
__global__ __launch_bounds__(TPB) void minpass_kernel(
        const float4* __restrict__ pa, const float4* __restrict__ pb,
        int* __restrict__ pmins, int n) {
    const int SB = n / (TPB * R);
    const int CH = n / CHUNKS;
    int b = blockIdx.x;
    int dir = b / (SB * CHUNKS);
    int rem = b % (SB * CHUNKS);
    int chunk = rem / SB;
    int sblk = rem % SB;
    const float4* __restrict__ src = dir ? pb : pa;
    const float4* __restrict__ tgt = dir ? pa : pb;

    __shared__ float4 tile[256];  // CH == 256
    int base = chunk * CH;
    for (int i = threadIdx.x; i < CH; i += TPB)
        tile[i] = tgt[base + i];

    float ax[R], ay[R], az[R], sw[R], m[R];
    int s0 = sblk * TPB * R + threadIdx.x;  // stride-TPB between r's: coalesced
#pragma unroll
    for (int r = 0; r < R; ++r) {
        float4 s = src[s0 + r * TPB];
        ax[r] = -2.0f * s.x; ay[r] = -2.0f * s.y; az[r] = -2.0f * s.z;
        sw[r] = s.w; m[r] = __builtin_inff();
    }
    __syncthreads();

#pragma unroll 4
    for (int j = 0; j < CH; ++j) {
        float4 p = tile[j];  // broadcast read, conflict-free
#pragma unroll
        for (int r = 0; r < R; ++r) {
            float d = fmaf(ax[r], p.x, fmaf(ay[r], p.y, fmaf(az[r], p.z, p.w)));
            m[r] = fminf(m[r], d);
        }
    }

    // full sq-dist >= 0 (mod ~1e-7 rounding) -> signed-int atomicMin is order-correct
#pragma unroll
    for (int r = 0; r < R; ++r)
        atomicMin(&pmins[dir * n + s0 + r * TPB], __float_as_int(m[r] + sw[r]));
}

// Single block: sum all 2n mins, out = sum/(2n)  (== (mean0+mean1)/2).
__global__ __launch_bounds__(1024) void finalize_kernel(
        const int* __restrict__ pmins, float* __restrict__ out, int n) {
    float sum = 0.0f;
    for (int i = threadIdx.x; i < 2 * n; i += 1024)
        sum += __int_as_float(pmins[i]);
    for (int off = 32; off > 0; off >>= 1)
        sum += __shfl_down(sum, off, 64);
    __shared__ float wsum[16];
    int lane = threadIdx.x & 63, wid = threadIdx.x >> 6;
    if (lane == 0) wsum[wid] = sum;
    __syncthreads();
    if (threadIdx.x == 0) {
        float t = 0.0f;
        for (int w = 0; w < 16; ++w) t += wsum[w];
        out[0] = t / (float)(2 * n);
    }
}

extern "C" void kernel_launch(void* const* d_in, const int* in_sizes, int n_in,
                              void* d_out, int out_size, void* d_ws, size_t ws_size,
                              hipStream_t stream) {
    const float* a = (const float*)d_in[0];
    const float* b = (const float*)d_in[1];
    int n = in_sizes[0] / 3;  // 16384
    float* out = (float*)d_out;
    char* ws = (char*)d_ws;
    float4* pa = (float4*)(ws + 256);
    float4* pb = pa + n;
    int* pmins = (int*)(ws + 256 + 2 * (size_t)n * sizeof(float4));  // 2n ints

    prep_kernel<<<(2 * n + TPB - 1) / TPB, TPB, 0, stream>>>(a, b, pa, pb, pmins, n);
    int SB = n / (TPB * R);
    minpass_kernel<<<2 * SB * CHUNKS, TPB, 0, stream>>>(pa, pb, pmins, n);
    finalize_kernel<<<1, 1024, 0, stream>>>(pmins, out, n);
}

// Round 3
// 101.115 us; speedup vs baseline: 2.8039x; 1.0131x over previous
//
#include <hip/hip_runtime.h>

#define TPB 256
#define R 16          // source points per lane (1 ds_read feeds 64 VALU insts)
#define CHUNKS 128    // target-dim chunking for grid parallelism
// n=16384: SB = n/(TPB*R) = 4 source-blocks/dir; CH = n/CHUNKS = 128 targets/chunk
// grid = 2*SB*CHUNKS = 1024 blocks = 4 blocks/CU

// Pack {x,y,z,|p|^2} for both sets; init pmins to +inf.
__global__ __launch_bounds__(TPB) void prep_kernel(
        const float* __restrict__ a, const float* __restrict__ b,
        float4* __restrict__ pa, float4* __restrict__ pb,
        int* __restrict__ pmins, int n) {
    int idx = blockIdx.x * blockDim.x + threadIdx.x;
    if (idx < n) {
        float x = a[3 * idx], y = a[3 * idx + 1], z = a[3 * idx + 2];
        pa[idx] = make_float4(x, y, z, x * x + y * y + z * z);
    } else if (idx < 2 * n) {
        int i = idx - n;
        float x = b[3 * i], y = b[3 * i + 1], z = b[3 * i + 2];
        pb[i] = make_float4(x, y, z, x * x + y * y + z * z);
    }
    if (idx < 2 * n) pmins[idx] = 0x7f800000;  // +inf
}

// min_t(|s-t|^2) = |s|^2 + min_t(|t|^2 - 2 s.t)
__global__ __launch_bounds__(TPB) void minpass_kernel(
        const float4* __restrict__ pa, const float4* __restrict__ pb,
        int* __restrict__ pmins, int n) {
    const int SB = n / (TPB * R);
    const int CH = n / CHUNKS;
    int b = blockIdx.x;
    int dir = b / (SB * CHUNKS);
    int rem = b % (SB * CHUNKS);
    int chunk = rem / SB;
    int sblk = rem % SB;
    const float4* __restrict__ src = dir ? pb : pa;
    const float4* __restrict__ tgt = dir ? pa : pb;

    __shared__ float4 tile[128];  // CH == 128
    int base = chunk * CH;
    for (int i = threadIdx.x; i < CH; i += TPB)
        tile[i] = tgt[base + i];

    float ax[R], ay[R], az[R], sw[R], m[R];
    int s0 = sblk * TPB * R + threadIdx.x;  // stride-TPB between r's: coalesced
#pragma unroll
    for (int r = 0; r < R; ++r) {
        float4 s = src[s0 + r * TPB];
        ax[r] = -2.0f * s.x; ay[r] = -2.0f * s.y; az[r] = -2.0f * s.z;
        sw[r] = s.w; m[r] = __builtin_inff();
    }
    __syncthreads();

#pragma unroll 4
    for (int j = 0; j < CH; ++j) {
        float4 p = tile[j];  // broadcast read, conflict-free
#pragma unroll
        for (int r = 0; r < R; ++r) {
            float d = fmaf(ax[r], p.x, fmaf(ay[r], p.y, fmaf(az[r], p.z, p.w)));
            m[r] = fminf(m[r], d);
        }
    }

    // sq-dists >= 0 (mod ~1e-7 rounding) -> signed-int atomicMin is order-correct
#pragma unroll
    for (int r = 0; r < R; ++r)
        atomicMin(&pmins[dir * n + s0 + r * TPB], __float_as_int(m[r] + sw[r]));
}

// 32 blocks x 256 threads: each thread sums one int4; atomicAdd + last-block out.
__global__ __launch_bounds__(TPB) void finalize_kernel(
        const int4* __restrict__ pmins, float* __restrict__ acc,
        unsigned* __restrict__ cnt, float* __restrict__ out, int n, int nblocks) {
    int i = blockIdx.x * TPB + threadIdx.x;  // i-th int4, total 2n/4
    int4 v = pmins[i];
    float sum = __int_as_float(v.x) + __int_as_float(v.y)
              + __int_as_float(v.z) + __int_as_float(v.w);
    for (int off = 32; off > 0; off >>= 1)
        sum += __shfl_down(sum, off, 64);
    __shared__ float wsum[TPB / 64];
    int lane = threadIdx.x & 63, wid = threadIdx.x >> 6;
    if (lane == 0) wsum[wid] = sum;
    __syncthreads();
    if (threadIdx.x == 0) {
        float t = 0.0f;
        for (int w = 0; w < TPB / 64; ++w) t += wsum[w];
        atomicAdd(acc, t);
        __threadfence();
        unsigned old = atomicAdd(cnt, 1u);
        if (old == (unsigned)(nblocks - 1)) {
            float a0 = atomicAdd(acc, 0.0f);  // device-scope coherent read
            out[0] = a0 / (float)(2 * n);
        }
    }
}

extern "C" void kernel_launch(void* const* d_in, const int* in_sizes, int n_in,
                              void* d_out, int out_size, void* d_ws, size_t ws_size,
                              hipStream_t stream) {
    const float* a = (const float*)d_in[0];
    const float* b = (const float*)d_in[1];
    int n = in_sizes[0] / 3;  // 16384
    float* out = (float*)d_out;
    char* ws = (char*)d_ws;
    float* acc = (float*)ws;                 // 1 float
    unsigned* cnt = (unsigned*)(ws + 8);     // 1 uint
    float4* pa = (float4*)(ws + 256);
    float4* pb = pa + n;
    int* pmins = (int*)(ws + 256 + 2 * (size_t)n * sizeof(float4));  // 2n ints

    hipMemsetAsync(ws, 0, 16, stream);
    prep_kernel<<<(2 * n + TPB - 1) / TPB, TPB, 0, stream>>>(a, b, pa, pb, pmins, n);
    int SB = n / (TPB * R);
    minpass_kernel<<<2 * SB * CHUNKS, TPB, 0, stream>>>(pa, pb, pmins, n);
    int fblocks = (2 * n / 4) / TPB;  // 32
    finalize_kernel<<<fblocks, TPB, 0, stream>>>((const int4*)pmins, acc, cnt, out, n, fblocks);
}